// Round 3
// baseline (136.501 us; speedup 1.0000x reference)
//
#include <hip/hip_runtime.h>

#define NS 65536
#define DD 32
#define RR 128
#define SPB 32            // samples per block
#define STR 132           // padded LDS row stride in floats (breaks power-of-2 column reads)

// Block = 256 threads = 4 waves = 2 wave-pairs. lane+pair -> rule (128 rules per pair),
// pair -> 16 samples; block covers 32 samples. All rule params in VGPRs (constant-index
// arrays only, fully unrolled -> SROA). Main loop is pure VALU + 2 ds_write_b32; all
// reductions deferred to a post-barrier LDS pass (no dependent swizzle chains).
__global__ __launch_bounds__(256, 3) void anfis_main(
    const float* __restrict__ X, const float* __restrict__ A,
    const float* __restrict__ B, const float* __restrict__ C,
    float* __restrict__ out_pred, float* __restrict__ out_str,
    float* __restrict__ out_norm)
{
    __shared__ float SBUF[SPB * STR];   // strengths, row = sample-in-block
    __shared__ float PBUF[SPB * STR];   // strength * rule_out
    __shared__ float pS[4][SPB];
    __shared__ float pD[4][SPB];
    __shared__ float scale_lds[SPB];

    const int tid  = threadIdx.x;
    const int w    = tid >> 6;
    const int lane = tid & 63;
    const int r    = ((w & 1) << 6) | lane;   // rule id
    const int pair = w >> 1;
    const int sbase = pair * 16;              // sample-in-block base for this pair
    const int nbase = blockIdx.x * SPB + sbase;

    // ---- per-thread rule params -> registers (constant indices only) ----
    float w_[DD], naw_[DD], ck_[DD], bias;
    {
        #pragma unroll
        for (int i = 0; i < 8; ++i) {
            float4 va = ((const float4*)(A + r * DD))[i];
            float4 vb = ((const float4*)(B + r * DD))[i];
            float wx = 0.8493218003f * __builtin_amdgcn_rcpf(fmaxf(vb.x, 1e-8f));
            float wy = 0.8493218003f * __builtin_amdgcn_rcpf(fmaxf(vb.y, 1e-8f));
            float wz = 0.8493218003f * __builtin_amdgcn_rcpf(fmaxf(vb.z, 1e-8f));
            float ww = 0.8493218003f * __builtin_amdgcn_rcpf(fmaxf(vb.w, 1e-8f));
            w_[4*i+0] = wx; naw_[4*i+0] = -va.x * wx;
            w_[4*i+1] = wy; naw_[4*i+1] = -va.y * wy;
            w_[4*i+2] = wz; naw_[4*i+2] = -va.z * wz;
            w_[4*i+3] = ww; naw_[4*i+3] = -va.w * ww;
        }
        #pragma unroll
        for (int d = 0; d < DD; ++d) ck_[d] = C[r * (DD + 1) + d];
        bias = C[r * (DD + 1) + DD];
    }

    // ---- main loop: 16 samples, straight-line after full unroll ----
    float* sb = &SBUF[sbase * STR + r];
    float* pb = &PBUF[sbase * STR + r];
    const float4* xp = (const float4*)(X + (size_t)nbase * DD);

    #pragma unroll
    for (int j = 0; j < 16; ++j) {
        float4 x0 = xp[8*j+0], x1 = xp[8*j+1], x2 = xp[8*j+2], x3 = xp[8*j+3];
        float4 x4 = xp[8*j+4], x5 = xp[8*j+5], x6 = xp[8*j+6], x7 = xp[8*j+7];
        float s0 = 0.f, s1 = 0.f, s2 = 0.f, s3 = 0.f;
        float r0 = bias, r1 = 0.f, r2 = 0.f, r3 = 0.f;
        #define Q(v, q) { float t; \
            t = fmaf(v.x, w_[4*(q)+0], naw_[4*(q)+0]); s0 = fmaf(t, t, s0); r0 = fmaf(v.x, ck_[4*(q)+0], r0); \
            t = fmaf(v.y, w_[4*(q)+1], naw_[4*(q)+1]); s1 = fmaf(t, t, s1); r1 = fmaf(v.y, ck_[4*(q)+1], r1); \
            t = fmaf(v.z, w_[4*(q)+2], naw_[4*(q)+2]); s2 = fmaf(t, t, s2); r2 = fmaf(v.z, ck_[4*(q)+2], r2); \
            t = fmaf(v.w, w_[4*(q)+3], naw_[4*(q)+3]); s3 = fmaf(t, t, s3); r3 = fmaf(v.w, ck_[4*(q)+3], r3); }
        Q(x0,0) Q(x1,1) Q(x2,2) Q(x3,3) Q(x4,4) Q(x5,5) Q(x6,6) Q(x7,7)
        #undef Q
        float st = __builtin_amdgcn_exp2f(-((s0 + s1) + (s2 + s3)));
        float ro = (r0 + r1) + (r2 + r3);
        sb[j * STR] = st;        // 64 consecutive dwords per wave: conflict-free
        pb[j * STR] = st * ro;
    }
    __syncthreads();

    // ---- per-sample sums over rules: contiguous b128 reads, stride-132 rows (4-way max) ----
    if (tid < 128) {
        int s = tid & 31, q = tid >> 5;
        const float4* srow = (const float4*)&SBUF[s * STR + q * 32];
        const float4* prow = (const float4*)&PBUF[s * STR + q * 32];
        float ss = 0.f, dd = 0.f;
        #pragma unroll
        for (int k = 0; k < 8; ++k) {
            float4 v = srow[k]; ss += (v.x + v.y) + (v.z + v.w);
            float4 p = prow[k]; dd += (p.x + p.y) + (p.z + p.w);
        }
        pS[q][s] = ss; pD[q][s] = dd;
    }
    __syncthreads();
    if (tid < SPB) {
        float ss = (pS[0][tid] + pS[1][tid]) + (pS[2][tid] + pS[3][tid]);
        float dd = (pD[0][tid] + pD[1][tid]) + (pD[2][tid] + pD[3][tid]);
        float sc = 1.0f / (ss + 1e-8f);
        out_pred[blockIdx.x * SPB + tid] = dd * sc;
        scale_lds[tid] = sc;
    }
    __syncthreads();

    // ---- flush strengths + normalized, float4-coalesced (512 B per sample row) ----
    #pragma unroll
    for (int it = 0; it < 4; ++it) {
        int f   = it * 256 + tid;     // float4 index over 32x32 tile
        int row = f >> 5;
        int col = f & 31;
        float4 v = *(const float4*)&SBUF[row * STR + col * 4];
        float sc = scale_lds[row];
        size_t base = ((size_t)(blockIdx.x * SPB + row)) * RR + col * 4;
        *(float4*)(out_str  + base) = v;
        *(float4*)(out_norm + base) = make_float4(v.x * sc, v.y * sc, v.z * sc, v.w * sc);
    }
}

extern "C" void kernel_launch(void* const* d_in, const int* in_sizes, int n_in,
                              void* d_out, int out_size, void* d_ws, size_t ws_size,
                              hipStream_t stream) {
    const float* X = (const float*)d_in[0];
    const float* A = (const float*)d_in[1];
    const float* B = (const float*)d_in[2];
    const float* C = (const float*)d_in[3];

    float* pred = (float*)d_out;
    float* str  = pred + NS;
    float* nrm  = str + (size_t)NS * RR;

    anfis_main<<<dim3(NS / SPB), dim3(256), 0, stream>>>(X, A, B, C, pred, str, nrm);
}

// Round 4
// 107.808 us; speedup vs baseline: 1.2661x; 1.2661x over previous
//
#include <hip/hip_runtime.h>

#define NS 65536
#define DD 32
#define RR 128
#define SPB 16            // samples per block
#define STR 132           // padded LDS row stride (floats)

// Block = 128 threads = 2 waves; thread == rule (0..127). Block covers 16 samples,
// indexed ONLY by blockIdx => X-row loads are provably uniform -> s_load into SGPRs
// (zero VGPR cost, SMEM pipe, SGPR double-buffered). Rule params live in VGPRs
// (~97/lane, fits under the 128-cap of __launch_bounds__(128,4) so no demotion).
// Main loop: 3 VALU ops per (n,r,d) + exp2 + 2 ds_write. Reductions deferred to a
// post-barrier LDS pass.
__global__ __launch_bounds__(128, 4) void anfis_main(
    const float* __restrict__ X, const float* __restrict__ A,
    const float* __restrict__ B, const float* __restrict__ C,
    float* __restrict__ out_pred, float* __restrict__ out_str,
    float* __restrict__ out_norm)
{
    __shared__ float SBUF[SPB * STR];   // strengths, row = sample-in-block
    __shared__ float PBUF[SPB * STR];   // strength * rule_out
    __shared__ float pS[SPB][8];
    __shared__ float pD[SPB][8];
    __shared__ float scale_lds[SPB];

    const int tid   = threadIdx.x;      // rule id
    const int nbase = blockIdx.x * SPB;

    // ---- per-thread rule params -> VGPRs (loaded once) ----
    float w_[DD], naw_[DD], ck_[DD], bias;
    {
        const float4* av = (const float4*)(A + tid * DD);
        const float4* bv = (const float4*)(B + tid * DD);
        #pragma unroll
        for (int i = 0; i < 8; ++i) {
            float4 va = av[i], vb = bv[i];
            float w0 = 0.8493218003f * __builtin_amdgcn_rcpf(fmaxf(vb.x, 1e-8f));
            float w1 = 0.8493218003f * __builtin_amdgcn_rcpf(fmaxf(vb.y, 1e-8f));
            float w2 = 0.8493218003f * __builtin_amdgcn_rcpf(fmaxf(vb.z, 1e-8f));
            float w3 = 0.8493218003f * __builtin_amdgcn_rcpf(fmaxf(vb.w, 1e-8f));
            w_[4*i+0] = w0; naw_[4*i+0] = -va.x * w0;
            w_[4*i+1] = w1; naw_[4*i+1] = -va.y * w1;
            w_[4*i+2] = w2; naw_[4*i+2] = -va.z * w2;
            w_[4*i+3] = w3; naw_[4*i+3] = -va.w * w3;
        }
        #pragma unroll
        for (int d = 0; d < DD; ++d) ck_[d] = C[tid * (DD + 1) + d];
        bias = C[tid * (DD + 1) + DD];
    }

    const float* Xg = X + (size_t)nbase * DD;   // uniform base (blockIdx only)

    float xa[DD], xb[DD];   // uniform values -> SGPRs
#define LOADX(arr, jj) { _Pragma("unroll") \
    for (int i = 0; i < DD; ++i) arr[i] = Xg[(jj) * DD + i]; }

#define COMPUTE(arr, jj) { \
    float s0 = 0.f, s1 = 0.f, s2 = 0.f, s3 = 0.f; \
    float r0 = bias, r1 = 0.f, r2 = 0.f, r3 = 0.f; \
    _Pragma("unroll") \
    for (int d = 0; d < DD; d += 4) { \
        float t0 = fmaf(arr[d+0], w_[d+0], naw_[d+0]); s0 = fmaf(t0, t0, s0); r0 = fmaf(arr[d+0], ck_[d+0], r0); \
        float t1 = fmaf(arr[d+1], w_[d+1], naw_[d+1]); s1 = fmaf(t1, t1, s1); r1 = fmaf(arr[d+1], ck_[d+1], r1); \
        float t2 = fmaf(arr[d+2], w_[d+2], naw_[d+2]); s2 = fmaf(t2, t2, s2); r2 = fmaf(arr[d+2], ck_[d+2], r2); \
        float t3 = fmaf(arr[d+3], w_[d+3], naw_[d+3]); s3 = fmaf(t3, t3, s3); r3 = fmaf(arr[d+3], ck_[d+3], r3); \
    } \
    float st = __builtin_amdgcn_exp2f(-((s0 + s1) + (s2 + s3))); \
    float ro = (r0 + r1) + (r2 + r3); \
    SBUF[(jj) * STR + tid] = st; \
    PBUF[(jj) * STR + tid] = st * ro; }

    LOADX(xa, 0)
    for (int j = 0; j < SPB; j += 2) {
        LOADX(xb, j + 1)                    // prefetch j+1 while computing j
        COMPUTE(xa, j)
        if (j + 2 < SPB) LOADX(xa, j + 2)   // prefetch j+2 while computing j+1
        COMPUTE(xb, j + 1)
    }
#undef LOADX
#undef COMPUTE
    __syncthreads();

    // ---- per-sample sums over rules: 128 threads = 16 samples x 8 octants ----
    {
        int s = tid >> 3, o = tid & 7;      // 16B-group o covers 16 floats
        const float4* srow = (const float4*)&SBUF[s * STR + o * 16];
        const float4* prow = (const float4*)&PBUF[s * STR + o * 16];
        float ss = 0.f, dd = 0.f;
        #pragma unroll
        for (int k = 0; k < 4; ++k) {
            float4 v = srow[k]; ss += (v.x + v.y) + (v.z + v.w);
            float4 p = prow[k]; dd += (p.x + p.y) + (p.z + p.w);
        }
        pS[s][o] = ss; pD[s][o] = dd;
    }
    __syncthreads();
    if (tid < SPB) {
        float ss = 0.f, dd = 0.f;
        #pragma unroll
        for (int o = 0; o < 8; ++o) { ss += pS[tid][o]; dd += pD[tid][o]; }
        float sc = 1.0f / (ss + 1e-8f);
        out_pred[nbase + tid] = dd * sc;
        scale_lds[tid] = sc;
    }
    __syncthreads();

    // ---- flush strengths + normalized, float4-coalesced (1 KB contiguous per wave) ----
    #pragma unroll
    for (int it = 0; it < 4; ++it) {
        int f   = it * 128 + tid;       // float4 index over 16x32 tile
        int row = f >> 5;
        int col = f & 31;
        float4 v = *(const float4*)&SBUF[row * STR + col * 4];
        float sc = scale_lds[row];
        size_t base = ((size_t)(nbase + row)) * RR + col * 4;
        *(float4*)(out_str  + base) = v;
        *(float4*)(out_norm + base) = make_float4(v.x * sc, v.y * sc, v.z * sc, v.w * sc);
    }
}

extern "C" void kernel_launch(void* const* d_in, const int* in_sizes, int n_in,
                              void* d_out, int out_size, void* d_ws, size_t ws_size,
                              hipStream_t stream) {
    const float* X = (const float*)d_in[0];
    const float* A = (const float*)d_in[1];
    const float* B = (const float*)d_in[2];
    const float* C = (const float*)d_in[3];

    float* pred = (float*)d_out;
    float* str  = pred + NS;
    float* nrm  = str + (size_t)NS * RR;

    anfis_main<<<dim3(NS / SPB), dim3(128), 0, stream>>>(X, A, B, C, pred, str, nrm);
}